// Round 1
// baseline (654.521 us; speedup 1.0000x reference)
//
#include <hip/hip_runtime.h>
#include <math.h>

#define N_NODES 50000
#define N_EDGES 800000
#define F 64
#define R 32
#define C3F 192   // 3*F
#define CAP 48    // bucket capacity; Poisson(16) max row ~45, +8 sigma
#define MLP_BLOCKS ((N_NODES + 31) / 32)
#define FILL_BLOCKS ((N_EDGES + 255) / 256)

#define REP32(X) X(0) X(1) X(2) X(3) X(4) X(5) X(6) X(7) \
                 X(8) X(9) X(10) X(11) X(12) X(13) X(14) X(15) \
                 X(16) X(17) X(18) X(19) X(20) X(21) X(22) X(23) \
                 X(24) X(25) X(26) X(27) X(28) X(29) X(30) X(31)

// ---------------------------------------------------------------------------
// Fused MLP + bucket-fill (independent work, one dispatch). UNCHANGED.
// Blocks [0, MLP_BLOCKS): phi = silu(s @ W1 + b1) @ W2 + b2
// Blocks [MLP_BLOCKS, +FILL_BLOCKS): bucket[i][pos] = (e, j)
// ---------------------------------------------------------------------------
__global__ __launch_bounds__(256) void mlp_fill_kernel(
    const float* __restrict__ s, const float* __restrict__ W1,
    const float* __restrict__ b1, const float* __restrict__ W2,
    const float* __restrict__ b2, float* __restrict__ phi,
    const int* __restrict__ eidx, int* __restrict__ counts,
    int2* __restrict__ bucket)
{
    __shared__ float hid_s[32][68];

    if (blockIdx.x >= MLP_BLOCKS) {
        // ---- fill part ----
        int e = (blockIdx.x - MLP_BLOCKS) * 256 + threadIdx.x;
        if (e < N_EDGES) {
            int i = eidx[e];
            int j = eidx[N_EDGES + e];
            int pos = atomicAdd(&counts[i], 1);
            if (pos < CAP) bucket[(size_t)i * CAP + pos] = make_int2(e, j);
        }
        return;
    }

    // ---- MLP part ----
    int n = threadIdx.x >> 3;          // 0..31 local node
    int seg = threadIdx.x & 7;         // 0..7
    int node = blockIdx.x * 32 + n;
    bool live = node < N_NODES;

    if (live) {
        float sv[F];
        const float4* srow = (const float4*)(s + (size_t)node * F);
#pragma unroll
        for (int q = 0; q < F / 4; q++) {
            float4 t = srow[q];
            sv[4*q+0] = t.x; sv[4*q+1] = t.y; sv[4*q+2] = t.z; sv[4*q+3] = t.w;
        }
        float acc[8];
#pragma unroll
        for (int q = 0; q < 8; q++) acc[q] = b1[seg * 8 + q];
#pragma unroll
        for (int k = 0; k < F; k++) {
            float sk = sv[k];
            const float4* w = (const float4*)(W1 + (size_t)k * F + seg * 8);
            float4 w0 = w[0], w1 = w[1];
            acc[0] += sk * w0.x; acc[1] += sk * w0.y;
            acc[2] += sk * w0.z; acc[3] += sk * w0.w;
            acc[4] += sk * w1.x; acc[5] += sk * w1.y;
            acc[6] += sk * w1.z; acc[7] += sk * w1.w;
        }
#pragma unroll
        for (int q = 0; q < 8; q++) {
            float a = acc[q];
            hid_s[n][seg * 8 + q] = a / (1.f + __expf(-a));   // silu
        }
    }
    __syncthreads();

    if (!live) return;

    float hv[F];
#pragma unroll
    for (int q = 0; q < F; q++) hv[q] = hid_s[n][q];

    float acc[24];
#pragma unroll
    for (int q = 0; q < 24; q++) acc[q] = b2[seg * 24 + q];
#pragma unroll
    for (int k = 0; k < F; k++) {
        float hk = hv[k];
        const float4* w = (const float4*)(W2 + (size_t)k * C3F + seg * 24);
#pragma unroll
        for (int q4 = 0; q4 < 6; q4++) {
            float4 wv = w[q4];
            acc[q4*4+0] += hk * wv.x;
            acc[q4*4+1] += hk * wv.y;
            acc[q4*4+2] += hk * wv.z;
            acc[q4*4+3] += hk * wv.w;
        }
    }
    float4* o = (float4*)(phi + (size_t)node * C3F + seg * 24);
#pragma unroll
    for (int q4 = 0; q4 < 6; q4++)
        o[q4] = make_float4(acc[q4*4+0], acc[q4*4+1], acc[q4*4+2], acc[q4*4+3]);
}

// ---------------------------------------------------------------------------
// Gather kernel v2: 3 waves per node (one per output segment).
//   wave 0: x_s  = phi_s *W_s *fc       -> acc_s
//   wave 1: x_vv = phi_vv*W_vv*fc       -> acc_d += v[j][d]*x_vv
//   wave 2: x_vs = phi_vs*W_vs*fc       -> acc_d += x_vs*u[d]
// Each wave keeps only 32 named Wr scalars (fits in <64 VGPRs -> 8 waves/SIMD,
// no AGPR shuffling). Radial row for edge k+1 is rotated through named
// scalars so its s_loads issue a full iteration early. The 32-FMA dot
// product is split into 4 partial chains to avoid a serialized dep chain.
// Cross-wave dv combine via 768 B LDS once per node.
// ---------------------------------------------------------------------------
template<int W>
__device__ __forceinline__ void gather_seg(
    const float* __restrict__ v, const float* __restrict__ phi,
    const float* __restrict__ radial, const float* __restrict__ f_cut,
    const float* __restrict__ unit_vec, const float* __restrict__ Wr,
    const float* __restrict__ br, const int2* __restrict__ row,
    int cnt, int lane, float& racc0, float& racc1, float& racc2)
{
    constexpr int SEG = W * 64;

    // this wave's 32 Wr column entries -> named VGPRs
#define DECL_WR(r) float wr##r;
    REP32(DECL_WR)
#undef DECL_WR
#define LOAD_WR(r) wr##r = Wr[(r) * C3F + SEG + lane];
    REP32(LOAD_WR)
#undef LOAD_WR
    const float bseg = br[SEG + lane];

    float acc0 = 0.f, acc1 = 0.f, acc2 = 0.f;

    if (cnt > 0) {
        // ---- prologue: edge 0 state ----
        int2 ej0 = row[0];
        int e = __builtin_amdgcn_readfirstlane(ej0.x);
        int j = __builtin_amdgcn_readfirstlane(ej0.y);

        float p = phi[(size_t)j * C3F + SEG + lane];
        float va = 0.f, vb = 0.f, vc = 0.f;
        if constexpr (W == 1) {
            const float* vj = v + (size_t)j * C3F;
            va = vj[lane]; vb = vj[64 + lane]; vc = vj[128 + lane];
        }
        float fc = f_cut[e];
        float u0 = 0.f, u1 = 0.f, u2 = 0.f;
        if constexpr (W == 2) {
            u0 = unit_vec[e * 3 + 0];
            u1 = unit_vec[e * 3 + 1];
            u2 = unit_vec[e * 3 + 2];
        }
        // current radial row (uniform address -> scalar loads/SGPRs)
#define DECL_CR(r) float cr##r;
        REP32(DECL_CR)
#undef DECL_CR
        {
            const float* rp = radial + (size_t)e * R;
#define LOAD_CR(r) cr##r = rp[r];
            REP32(LOAD_CR)
#undef LOAD_CR
        }

        for (int k = 0; k < cnt; ++k) {
            // ---- prefetch edge k+1 (loads issue here, consumed next iter) --
            int e_n = e, j_n = j;
            if (k + 1 < cnt) {
                int2 ejn = row[k + 1];
                e_n = __builtin_amdgcn_readfirstlane(ejn.x);
                j_n = __builtin_amdgcn_readfirstlane(ejn.y);
            }
            float p_n = phi[(size_t)j_n * C3F + SEG + lane];
            float nva = 0.f, nvb = 0.f, nvc = 0.f;
            if constexpr (W == 1) {
                const float* vn = v + (size_t)j_n * C3F;
                nva = vn[lane]; nvb = vn[64 + lane]; nvc = vn[128 + lane];
            }
            float fc_n = f_cut[e_n];
            float nu0 = 0.f, nu1 = 0.f, nu2 = 0.f;
            if constexpr (W == 2) {
                nu0 = unit_vec[e_n * 3 + 0];
                nu1 = unit_vec[e_n * 3 + 1];
                nu2 = unit_vec[e_n * 3 + 2];
            }
#define DECL_NR(r) float nr##r;
            REP32(DECL_NR)
#undef DECL_NR
            {
                const float* rpn = radial + (size_t)e_n * R;
#define LOAD_NR(r) nr##r = rpn[r];
                REP32(LOAD_NR)
#undef LOAD_NR
            }

            // ---- compute with current state: W_seg = radial_e @ Wr + br ----
            float wsum[4] = { bseg, 0.f, 0.f, 0.f };   // 4 chains, const idx
#define FMA_WR(r) wsum[(r) & 3] += cr##r * wr##r;
            REP32(FMA_WR)
#undef FMA_WR
            float ws = (wsum[0] + wsum[1]) + (wsum[2] + wsum[3]);

            float x = p * ws * fc;
            if constexpr (W == 0) {
                acc0 += x;
            } else if constexpr (W == 1) {
                acc0 += va * x; acc1 += vb * x; acc2 += vc * x;
            } else {
                acc0 += x * u0; acc1 += x * u1; acc2 += x * u2;
            }

            // ---- rotate pipeline ----
            e = e_n; j = j_n;
            p = p_n; fc = fc_n;
            if constexpr (W == 1) { va = nva; vb = nvb; vc = nvc; }
            if constexpr (W == 2) { u0 = nu0; u1 = nu1; u2 = nu2; }
#define ROT_R(r) cr##r = nr##r;
            REP32(ROT_R)
#undef ROT_R
        }
    }

    racc0 = acc0; racc1 = acc1; racc2 = acc2;
}

__global__ __launch_bounds__(192, 6) void gather_kernel(
    const float* __restrict__ s, const float* __restrict__ v,
    const float* __restrict__ phi, const float* __restrict__ radial,
    const float* __restrict__ f_cut, const float* __restrict__ unit_vec,
    const float* __restrict__ Wr, const float* __restrict__ br,
    const int* __restrict__ counts, const int2* __restrict__ bucket,
    float* __restrict__ out_s, float* __restrict__ out_v)
{
    const int lane = threadIdx.x & 63;
    const int w    = threadIdx.x >> 6;      // 0..2 = segment wave
    const int node = blockIdx.x;

    __shared__ float tmp[3][64];

    int cnt = __builtin_amdgcn_readfirstlane(counts[node]);
    cnt = cnt < CAP ? cnt : CAP;
    const int2* row = bucket + (size_t)node * CAP;

    float a0 = 0.f, a1 = 0.f, a2 = 0.f;
    if (w == 0)
        gather_seg<0>(v, phi, radial, f_cut, unit_vec, Wr, br, row, cnt, lane, a0, a1, a2);
    else if (w == 1)
        gather_seg<1>(v, phi, radial, f_cut, unit_vec, Wr, br, row, cnt, lane, a0, a1, a2);
    else
        gather_seg<2>(v, phi, radial, f_cut, unit_vec, Wr, br, row, cnt, lane, a0, a1, a2);

    // wave2 publishes its x_vs*u accumulators; wave1 folds them in
    if (w == 2) { tmp[0][lane] = a0; tmp[1][lane] = a1; tmp[2][lane] = a2; }
    __syncthreads();

    if (w == 0) {
        out_s[(size_t)node * F + lane] = s[(size_t)node * F + lane] + a0;
    } else if (w == 1) {
        const float* vi = v + (size_t)node * C3F;
        float* ovi = out_v + (size_t)node * C3F;
        ovi[lane]       = vi[lane]       + a0 + tmp[0][lane];
        ovi[64 + lane]  = vi[64 + lane]  + a1 + tmp[1][lane];
        ovi[128 + lane] = vi[128 + lane] + a2 + tmp[2][lane];
    }
}

// ---------------------------------------------------------------------------
extern "C" void kernel_launch(void* const* d_in, const int* in_sizes, int n_in,
                              void* d_out, int out_size, void* d_ws, size_t ws_size,
                              hipStream_t stream)
{
    const float* s      = (const float*)d_in[0];
    const float* v      = (const float*)d_in[1];
    const float* radial = (const float*)d_in[2];
    const float* f_cut  = (const float*)d_in[3];
    const float* unit   = (const float*)d_in[4];
    const int*   eidx   = (const int*)  d_in[5];
    const float* W1     = (const float*)d_in[6];
    const float* b1     = (const float*)d_in[7];
    const float* W2     = (const float*)d_in[8];
    const float* b2     = (const float*)d_in[9];
    const float* Wr     = (const float*)d_in[10];
    const float* br     = (const float*)d_in[11];

    float* out   = (float*)d_out;
    float* out_s = out;
    float* out_v = out + (size_t)N_NODES * F;

    // workspace layout (~58 MB)
    float* phi    = (float*)d_ws;                          // 50000*192 f32
    int*   counts = (int*)(phi + (size_t)N_NODES * C3F);   // 50000
    int2*  bucket = (int2*)(counts + N_NODES);             // 50000*48 int2

    hipMemsetAsync(counts, 0, N_NODES * sizeof(int), stream);

    mlp_fill_kernel<<<MLP_BLOCKS + FILL_BLOCKS, 256, 0, stream>>>(
        s, W1, b1, W2, b2, phi, eidx, counts, bucket);

    gather_kernel<<<N_NODES, 192, 0, stream>>>(
        s, v, phi, radial, f_cut, unit, Wr, br,
        counts, bucket, out_s, out_v);
}

// Round 2
// 572.297 us; speedup vs baseline: 1.1437x; 1.1437x over previous
//
#include <hip/hip_runtime.h>
#include <math.h>

#define N_NODES 50000
#define N_EDGES 800000
#define F 64
#define R 32
#define C3F 192   // 3*F
#define CAP 48    // bucket capacity; Poisson(16) max row ~45, +8 sigma
#define CSTRIDE 16  // counters padded to one per 64B line (atomic contention)
#define MLP_BLOCKS ((N_NODES + 31) / 32)
#define FILL_BLOCKS ((N_EDGES + 255) / 256)

#define REP32(X) X(0) X(1) X(2) X(3) X(4) X(5) X(6) X(7) \
                 X(8) X(9) X(10) X(11) X(12) X(13) X(14) X(15) \
                 X(16) X(17) X(18) X(19) X(20) X(21) X(22) X(23) \
                 X(24) X(25) X(26) X(27) X(28) X(29) X(30) X(31)

// ---------------------------------------------------------------------------
// Fused MLP + bucket-fill. MLP part unchanged. Fill part: counters padded to
// one per 64B cache line — 800K device-scope atomics previously hit 16
// counters/line (cross-XCD line serialization suspected for the ~290us cost).
// ---------------------------------------------------------------------------
__global__ __launch_bounds__(256) void mlp_fill_kernel(
    const float* __restrict__ s, const float* __restrict__ W1,
    const float* __restrict__ b1, const float* __restrict__ W2,
    const float* __restrict__ b2, float* __restrict__ phi,
    const int* __restrict__ eidx, int* __restrict__ counts,
    int2* __restrict__ bucket)
{
    __shared__ float hid_s[32][68];

    if (blockIdx.x >= MLP_BLOCKS) {
        // ---- fill part ----
        int e = (blockIdx.x - MLP_BLOCKS) * 256 + threadIdx.x;
        if (e < N_EDGES) {
            int i = eidx[e];
            int j = eidx[N_EDGES + e];
            int pos = atomicAdd(&counts[i * CSTRIDE], 1);
            if (pos < CAP) bucket[(size_t)i * CAP + pos] = make_int2(e, j);
        }
        return;
    }

    // ---- MLP part ----
    int n = threadIdx.x >> 3;          // 0..31 local node
    int seg = threadIdx.x & 7;         // 0..7
    int node = blockIdx.x * 32 + n;
    bool live = node < N_NODES;

    if (live) {
        float sv[F];
        const float4* srow = (const float4*)(s + (size_t)node * F);
#pragma unroll
        for (int q = 0; q < F / 4; q++) {
            float4 t = srow[q];
            sv[4*q+0] = t.x; sv[4*q+1] = t.y; sv[4*q+2] = t.z; sv[4*q+3] = t.w;
        }
        float acc[8];
#pragma unroll
        for (int q = 0; q < 8; q++) acc[q] = b1[seg * 8 + q];
#pragma unroll
        for (int k = 0; k < F; k++) {
            float sk = sv[k];
            const float4* w = (const float4*)(W1 + (size_t)k * F + seg * 8);
            float4 w0 = w[0], w1 = w[1];
            acc[0] += sk * w0.x; acc[1] += sk * w0.y;
            acc[2] += sk * w0.z; acc[3] += sk * w0.w;
            acc[4] += sk * w1.x; acc[5] += sk * w1.y;
            acc[6] += sk * w1.z; acc[7] += sk * w1.w;
        }
#pragma unroll
        for (int q = 0; q < 8; q++) {
            float a = acc[q];
            hid_s[n][seg * 8 + q] = a / (1.f + __expf(-a));   // silu
        }
    }
    __syncthreads();

    if (!live) return;

    float hv[F];
#pragma unroll
    for (int q = 0; q < F; q++) hv[q] = hid_s[n][q];

    float acc[24];
#pragma unroll
    for (int q = 0; q < 24; q++) acc[q] = b2[seg * 24 + q];
#pragma unroll
    for (int k = 0; k < F; k++) {
        float hk = hv[k];
        const float4* w = (const float4*)(W2 + (size_t)k * C3F + seg * 24);
#pragma unroll
        for (int q4 = 0; q4 < 6; q4++) {
            float4 wv = w[q4];
            acc[q4*4+0] += hk * wv.x;
            acc[q4*4+1] += hk * wv.y;
            acc[q4*4+2] += hk * wv.z;
            acc[q4*4+3] += hk * wv.w;
        }
    }
    float4* o = (float4*)(phi + (size_t)node * C3F + seg * 24);
#pragma unroll
    for (int q4 = 0; q4 < 6; q4++)
        o[q4] = make_float4(acc[q4*4+0], acc[q4*4+1], acc[q4*4+2], acc[q4*4+3]);
}

// ---------------------------------------------------------------------------
// Gather v3: ONE wave per node (96 FMA/edge hides latency, no redundant
// per-edge scalar loads), __launch_bounds__(64,4) caps the unified reg file
// at 128 -> 4 waves/SIMD with NO AGPR shuffling. The 96 Wr values are pinned
// in VGPRs via inline-asm keep-alives (v2 showed the compiler otherwise sinks
// the loads into the loop: VGPR_Count=28 < 32 named values). Radial row,
// f_cut and unit_vec for edge k+1 are rotated through named SGPR-resident
// scalars (worked in v2: SGPR_Count=96); phi/v rows depth-1 pipelined.
// ---------------------------------------------------------------------------
__global__ __launch_bounds__(64, 4) void gather_kernel(
    const float* __restrict__ s, const float* __restrict__ v,
    const float* __restrict__ phi, const float* __restrict__ radial,
    const float* __restrict__ f_cut, const float* __restrict__ unit_vec,
    const float* __restrict__ Wr, const float* __restrict__ br,
    const int* __restrict__ counts, const int2* __restrict__ bucket,
    float* __restrict__ out_s, float* __restrict__ out_v)
{
    const int lane = threadIdx.x;      // 0..63
    const int node = blockIdx.x;

    // 96 named Wr column values -> forced VGPR residency
#define DECL_WR(r) float wrs##r, wrv##r, wrq##r;
    REP32(DECL_WR)
#undef DECL_WR
#define LOAD_WR(r) { const float* w_ = Wr + (r) * C3F; \
                     wrs##r = w_[lane]; wrv##r = w_[64 + lane]; \
                     wrq##r = w_[128 + lane]; }
    REP32(LOAD_WR)
#undef LOAD_WR
    // keep-alive: opaque redefinition forbids remat/sinking of the 96 loads
#define KA3(r) , "+v"(wrs##r), "+v"(wrv##r), "+v"(wrq##r)
    asm volatile("" : "+v"(wrs0) KA3(1) KA3(2) KA3(3) KA3(4) KA3(5) KA3(6) KA3(7), "+v"(wrv0), "+v"(wrq0));
    asm volatile("" : "+v"(wrs8) KA3(9) KA3(10) KA3(11) KA3(12) KA3(13) KA3(14) KA3(15), "+v"(wrv8), "+v"(wrq8));
    asm volatile("" : "+v"(wrs16) KA3(17) KA3(18) KA3(19) KA3(20) KA3(21) KA3(22) KA3(23), "+v"(wrv16), "+v"(wrq16));
    asm volatile("" : "+v"(wrs24) KA3(25) KA3(26) KA3(27) KA3(28) KA3(29) KA3(30) KA3(31), "+v"(wrv24), "+v"(wrq24));
#undef KA3

    const float b_s = br[lane], b_vv = br[64 + lane], b_vs = br[128 + lane];

    float acc_s = 0.f, acc_v0 = 0.f, acc_v1 = 0.f, acc_v2 = 0.f;

    int cnt = __builtin_amdgcn_readfirstlane(counts[node * CSTRIDE]);
    cnt = cnt < CAP ? cnt : CAP;
    const int2* row = bucket + (size_t)node * CAP;

    if (cnt > 0) {
        // ---- prologue: full state for edge 0 ----
        int2 ej0 = row[0];
        int e = __builtin_amdgcn_readfirstlane(ej0.x);
        int j = __builtin_amdgcn_readfirstlane(ej0.y);

        const float* pj = phi + (size_t)j * C3F;
        const float* vj = v + (size_t)j * C3F;
        float ps = pj[lane], pvv = pj[64 + lane], pvs = pj[128 + lane];
        float va = vj[lane], vb = vj[64 + lane], vc = vj[128 + lane];

        float fc = f_cut[e];                    // uniform -> SGPR
        float u0 = unit_vec[e * 3 + 0];
        float u1 = unit_vec[e * 3 + 1];
        float u2 = unit_vec[e * 3 + 2];
#define DECL_CR(r) float cr##r;
        REP32(DECL_CR)
#undef DECL_CR
        {
            const float* rp = radial + (size_t)e * R;   // uniform -> s_load
#define LOAD_CR(r) cr##r = rp[r];
            REP32(LOAD_CR)
#undef LOAD_CR
        }

        for (int k = 0; k < cnt; ++k) {
            // ---- prefetch edge k+1: issued here, consumed next iteration ---
            int e_n = e, j_n = j;
            if (k + 1 < cnt) {
                int2 ejn = row[k + 1];
                e_n = __builtin_amdgcn_readfirstlane(ejn.x);
                j_n = __builtin_amdgcn_readfirstlane(ejn.y);
            }
            const float* pn = phi + (size_t)j_n * C3F;
            const float* vn = v + (size_t)j_n * C3F;
            float nps = pn[lane], npvv = pn[64 + lane], npvs = pn[128 + lane];
            float nva = vn[lane], nvb = vn[64 + lane], nvc = vn[128 + lane];
            float fc_n = f_cut[e_n];
            float nu0 = unit_vec[e_n * 3 + 0];
            float nu1 = unit_vec[e_n * 3 + 1];
            float nu2 = unit_vec[e_n * 3 + 2];
#define DECL_NR(r) float nr##r;
            REP32(DECL_NR)
#undef DECL_NR
            {
                const float* rpn = radial + (size_t)e_n * R;
#define LOAD_NR(r) nr##r = rpn[r];
                REP32(LOAD_NR)
#undef LOAD_NR
            }

            // ---- compute edge k: W = radial @ Wr + br (3 indep FMA chains) -
            float ws = b_s, wvv = b_vv, wvs = b_vs;
#define FMA_WR(r) { ws  += cr##r * wrs##r; \
                    wvv += cr##r * wrv##r; \
                    wvs += cr##r * wrq##r; }
            REP32(FMA_WR)
#undef FMA_WR

            float xs  = ps  * ws  * fc;
            float xvv = pvv * wvv * fc;
            float xvs = pvs * wvs * fc;
            acc_s  += xs;
            acc_v0 += va * xvv + xvs * u0;
            acc_v1 += vb * xvv + xvs * u1;
            acc_v2 += vc * xvv + xvs * u2;

            // ---- rotate pipeline ----
            e = e_n; j = j_n;
            ps = nps; pvv = npvv; pvs = npvs;
            va = nva; vb = nvb; vc = nvc;
            fc = fc_n; u0 = nu0; u1 = nu1; u2 = nu2;
#define ROT_R(r) cr##r = nr##r;
            REP32(ROT_R)
#undef ROT_R
        }
    }

    out_s[(size_t)node * F + lane] = s[(size_t)node * F + lane] + acc_s;
    const float* vi = v + (size_t)node * C3F;
    float* ovi = out_v + (size_t)node * C3F;
    ovi[lane]       = vi[lane]       + acc_v0;
    ovi[64 + lane]  = vi[64 + lane]  + acc_v1;
    ovi[128 + lane] = vi[128 + lane] + acc_v2;
}

// ---------------------------------------------------------------------------
extern "C" void kernel_launch(void* const* d_in, const int* in_sizes, int n_in,
                              void* d_out, int out_size, void* d_ws, size_t ws_size,
                              hipStream_t stream)
{
    const float* s      = (const float*)d_in[0];
    const float* v      = (const float*)d_in[1];
    const float* radial = (const float*)d_in[2];
    const float* f_cut  = (const float*)d_in[3];
    const float* unit   = (const float*)d_in[4];
    const int*   eidx   = (const int*)  d_in[5];
    const float* W1     = (const float*)d_in[6];
    const float* b1     = (const float*)d_in[7];
    const float* W2     = (const float*)d_in[8];
    const float* b2     = (const float*)d_in[9];
    const float* Wr     = (const float*)d_in[10];
    const float* br     = (const float*)d_in[11];

    float* out   = (float*)d_out;
    float* out_s = out;
    float* out_v = out + (size_t)N_NODES * F;

    // workspace layout (~61 MB)
    float* phi    = (float*)d_ws;                                  // 50000*192 f32
    int*   counts = (int*)(phi + (size_t)N_NODES * C3F);           // 50000*16 (padded)
    int2*  bucket = (int2*)(counts + (size_t)N_NODES * CSTRIDE);   // 50000*48 int2

    hipMemsetAsync(counts, 0, (size_t)N_NODES * CSTRIDE * sizeof(int), stream);

    mlp_fill_kernel<<<MLP_BLOCKS + FILL_BLOCKS, 256, 0, stream>>>(
        s, W1, b1, W2, b2, phi, eidx, counts, bucket);

    gather_kernel<<<N_NODES, 64, 0, stream>>>(
        s, v, phi, radial, f_cut, unit, Wr, br,
        counts, bucket, out_s, out_v);
}